// Round 15
// baseline (1287.595 us; speedup 1.0000x reference)
//
#include <hip/hip_runtime.h>

#define BATCH 64
#define SEQ   4096
#define ISZ   64
#define RSZ   128

typedef float  f32x4_t __attribute__((ext_vector_type(4)));
typedef float  f32x2_t __attribute__((ext_vector_type(2)));
typedef __fp16 f16x2_t __attribute__((ext_vector_type(2)));

__device__ __forceinline__ float fast_tanh(float x) {
    float e = __expf(2.0f * x);
    return 1.0f - 2.0f / (e + 1.0f);
}

__device__ __forceinline__ float dot2(f16x2_t a, f16x2_t b, float c) {
#if __has_builtin(__builtin_amdgcn_fdot2)
    return __builtin_amdgcn_fdot2(a, b, c, false);
#else
    return fmaf((float)a.x, (float)b.x, fmaf((float)a.y, (float)b.y, c));
#endif
}

// x + cross-lane(x) via DPP — pure VALU, no DS ops.
// 0xB1 = quad_perm[1,0,3,2] (xor1), 0x4E = quad_perm[2,3,0,1] (xor2),
// 0x141 = row_half_mirror (lane l <-> l^7 within each 8-lane half-row).
template <int CTRL>
__device__ __forceinline__ float dpp_add(float x) {
    int y = __builtin_amdgcn_update_dpp(0, __builtin_bit_cast(int, x),
                                        CTRL, 0xF, 0xF, true);
    return x + __builtin_bit_cast(float, y);
}

// ---------------------------------------------------------------------------
// Kernel 1: projection. out[row][r] = tanh(sum_j x[row][j] * w_in[r][j])
// Same structure as rounds 1-14 (32 rows/block, LDS-staged wT and xs), but
// the inner product now uses packed v_pk_fma_f32 (f32x2 elementwise fma):
// 1024 scalar FMA -> 512 pk_fma per thread. f32 precision preserved.
// ---------------------------------------------------------------------------
__global__ __launch_bounds__(256) void proj_kernel(
        const float* __restrict__ x, const float* __restrict__ w_in,
        float* __restrict__ out) {
    __shared__ float wT[ISZ][RSZ];
    __shared__ float xs[32][ISZ];

    const int tid = threadIdx.x;

    for (int idx = tid; idx < RSZ * ISZ / 4; idx += 256) {
        const int r  = idx >> 4;
        const int j4 = (idx & 15) << 2;
        const float4 v = reinterpret_cast<const float4*>(w_in)[idx];
        wT[j4 + 0][r] = v.x; wT[j4 + 1][r] = v.y;
        wT[j4 + 2][r] = v.z; wT[j4 + 3][r] = v.w;
    }
    const long row0 = (long)blockIdx.x * 32;
    #pragma unroll
    for (int q = 0; q < 2; ++q) {
        const int idx = tid + q * 256;
        reinterpret_cast<float4*>(&xs[0][0])[idx] =
            reinterpret_cast<const float4*>(x + row0 * ISZ)[idx];
    }
    __syncthreads();

    const int rq = tid & 31;
    const int rp = tid >> 5;
    const int r0 = rq << 2;
    const int ra = rp << 2;

    f32x2_t acc[4][2] = {};              // [m][r-pair: {r0,r0+1},{r0+2,r0+3}]
    #pragma unroll
    for (int j4 = 0; j4 < ISZ; j4 += 4) {
        f32x4_t xv[4];
        #pragma unroll
        for (int m = 0; m < 4; ++m)
            xv[m] = *reinterpret_cast<const f32x4_t*>(&xs[ra + m][j4]);
        #pragma unroll
        for (int k = 0; k < 4; ++k) {
            const f32x4_t w = *reinterpret_cast<const f32x4_t*>(
                &wT[j4 + k][r0]);
            const f32x2_t w01 = w.xy, w23 = w.zw;
            #pragma unroll
            for (int m = 0; m < 4; ++m) {
                const float xm = k == 0 ? xv[m].x : k == 1 ? xv[m].y
                               : k == 2 ? xv[m].z : xv[m].w;
                f32x2_t xv2; xv2.x = xm; xv2.y = xm;
                acc[m][0] = __builtin_elementwise_fma(xv2, w01, acc[m][0]);
                acc[m][1] = __builtin_elementwise_fma(xv2, w23, acc[m][1]);
            }
        }
    }
    #pragma unroll
    for (int m = 0; m < 4; ++m) {
        float4 o;
        o.x = fast_tanh(acc[m][0].x); o.y = fast_tanh(acc[m][0].y);
        o.z = fast_tanh(acc[m][1].x); o.w = fast_tanh(acc[m][1].y);
        *reinterpret_cast<float4*>(&out[(row0 + ra + m) * RSZ + r0]) = o;
    }
}

// ---------------------------------------------------------------------------
// Kernel 2: sequential scan. Round-14 structure verbatim (1229 us proven:
// one block per batch, 4 waves; lane (grp = lane>>3, sl = lane&7) does rows
// r0..r0+3 x k-slice [16sl,16sl+16); packed-f16-in-float h LDS (2 ds_read
// _b128/lane, one float2 write); v_dot2_f32_f16; 12-DPP reduce; 4 redundant
// ACTs; stage ring + NT flush; 4-deep u prefetch; raw s_barrier +
// lgkmcnt(0)-only wait; float-typed LDS only — r11/r13's uint-typed LDS
// failed identically). ONE change: the dot uses 8 accumulators (4-deep dot2
// chains + pairwise add) instead of 4 (8-deep) — dependent-chain latency in
// the step's serial path drops ~half of the dot segment.
// ---------------------------------------------------------------------------
__global__ __launch_bounds__(256) void scan_kernel(
        const float* __restrict__ w_res, float* __restrict__ io) {
    __shared__ float hq[2][80];          // packed f16x2-in-float, dbuf (64 used)
    __shared__ float stage[16 * 128];    // 8 KB ring, slot = t & 15

    const int tid  = threadIdx.x;
    const int lane = tid & 63;
    const int wave = tid >> 6;
    const int grp  = lane >> 3;          // 8 output groups of 4
    const int sl   = lane & 7;           // 8 k-slices of 16
    const int r0   = wave * 32 + grp * 4;
    const int kb   = sl * 16;

    // W_res rows r0..r0+3, cols kb..kb+15 -> f16x2 (32 VGPRs)
    f16x2_t w2[4][8];
    #pragma unroll
    for (int rr = 0; rr < 4; ++rr) {
        #pragma unroll
        for (int kk = 0; kk < 16; kk += 4) {
            const f32x4_t v = *reinterpret_cast<const f32x4_t*>(
                &w_res[(r0 + rr) * RSZ + kb + kk]);
            w2[rr][kk / 2]     = __builtin_amdgcn_cvt_pkrtz(v.x, v.y);
            w2[rr][kk / 2 + 1] = __builtin_amdgcn_cvt_pkrtz(v.z, v.w);
        }
    }

    for (int i = tid; i < 2 * 80; i += 256) (&hq[0][0])[i] = 0.0f;

    float* const out = io + (long)blockIdx.x * (SEQ * RSZ);
    const int hrd = 8 * sl;              // float index of k-slice base
    const int hwr = 16 * wave + 2 * grp; // float index of own packed pair

    // 4-deep u prefetch ring (float4 per lane at r0 — verbatim round 6)
    float4 u[4];
    #pragma unroll
    for (int s = 0; s < 4; ++s)
        u[s] = *reinterpret_cast<const float4*>(&out[s * RSZ + r0]);
    float4 hreg = {0.f, 0.f, 0.f, 0.f};
    __syncthreads();

    // nh = 0.5*h + 0.5*tanh(v) = fma(0.5,h,0.5) - 1/(exp2(2*log2e*v)+1)
    #define ACT(HH, VV)                                                       \
        (fmaf(0.5f, (HH), 0.5f) -                                             \
         __builtin_amdgcn_rcpf(                                               \
             __builtin_amdgcn_exp2f((VV) * 2.885390082f) + 1.0f))

    #define STEP(S)                                                           \
    {                                                                         \
        int tp = t0 + (S) + 4;                                                \
        if (tp > SEQ - 1) tp = SEQ - 1;                                       \
        const float4 uc = u[(S) & 3];                                         \
        u[(S) & 3] = *reinterpret_cast<const float4*>(&out[tp * RSZ + r0]);   \
        const float4 p0 = *reinterpret_cast<const float4*>(                   \
            &hq[(S) & 1][hrd]);                                               \
        const float4 p1 = *reinterpret_cast<const float4*>(                   \
            &hq[(S) & 1][hrd + 4]);                                           \
        f16x2_t hv[8];                                                        \
        hv[0] = __builtin_bit_cast(f16x2_t, p0.x);                            \
        hv[1] = __builtin_bit_cast(f16x2_t, p0.y);                            \
        hv[2] = __builtin_bit_cast(f16x2_t, p0.z);                            \
        hv[3] = __builtin_bit_cast(f16x2_t, p0.w);                            \
        hv[4] = __builtin_bit_cast(f16x2_t, p1.x);                            \
        hv[5] = __builtin_bit_cast(f16x2_t, p1.y);                            \
        hv[6] = __builtin_bit_cast(f16x2_t, p1.z);                            \
        hv[7] = __builtin_bit_cast(f16x2_t, p1.w);                            \
        float b0 = 0.f, b1 = 0.f, b2 = 0.f, b3 = 0.f;                         \
        float c0 = 0.f, c1 = 0.f, c2 = 0.f, c3 = 0.f;                         \
        _Pragma("unroll")                                                     \
        for (int j = 0; j < 4; ++j) {                                         \
            b0 = dot2(hv[j], w2[0][j], b0);                                   \
            b1 = dot2(hv[j], w2[1][j], b1);                                   \
            b2 = dot2(hv[j], w2[2][j], b2);                                   \
            b3 = dot2(hv[j], w2[3][j], b3);                                   \
            c0 = dot2(hv[j + 4], w2[0][j + 4], c0);                           \
            c1 = dot2(hv[j + 4], w2[1][j + 4], c1);                           \
            c2 = dot2(hv[j + 4], w2[2][j + 4], c2);                           \
            c3 = dot2(hv[j + 4], w2[3][j + 4], c3);                           \
        }                                                                     \
        float a0 = b0 + c0, a1 = b1 + c1, a2 = b2 + c2, a3 = b3 + c3;         \
        a0 = dpp_add<0xB1>(a0);  a1 = dpp_add<0xB1>(a1);                      \
        a2 = dpp_add<0xB1>(a2);  a3 = dpp_add<0xB1>(a3);                      \
        a0 = dpp_add<0x4E>(a0);  a1 = dpp_add<0x4E>(a1);                      \
        a2 = dpp_add<0x4E>(a2);  a3 = dpp_add<0x4E>(a3);                      \
        a0 = dpp_add<0x141>(a0); a1 = dpp_add<0x141>(a1);                     \
        a2 = dpp_add<0x141>(a2); a3 = dpp_add<0x141>(a3);                     \
        float4 nh;                                                            \
        nh.x = ACT(hreg.x, uc.x + a0);                                        \
        nh.y = ACT(hreg.y, uc.y + a1);                                        \
        nh.z = ACT(hreg.z, uc.z + a2);                                        \
        nh.w = ACT(hreg.w, uc.w + a3);                                        \
        hreg = nh;                                                            \
        if (sl == 0) {                                                        \
            float2 pv;                                                        \
            pv.x = __builtin_bit_cast(float,                                  \
                       __builtin_amdgcn_cvt_pkrtz(nh.x, nh.y));               \
            pv.y = __builtin_bit_cast(float,                                  \
                       __builtin_amdgcn_cvt_pkrtz(nh.z, nh.w));               \
            *reinterpret_cast<float2*>(&hq[1 - ((S) & 1)][hwr]) = pv;         \
        } else if (sl == 1) {                                                 \
            *reinterpret_cast<float4*>(                                       \
                &stage[((t0 & 8) + (S)) * 128 + r0]) = nh;                    \
        }                                                                     \
        asm volatile("s_waitcnt lgkmcnt(0)" ::: "memory");                    \
        __builtin_amdgcn_s_barrier();                                         \
        asm volatile("" ::: "memory");                                        \
    }

    const int fstep = tid >> 5;          // 0..7: which step of the half
    const int felem = (tid & 31) * 4;    // 0..124: element quad

    for (int t0 = 0; t0 < SEQ; t0 += 8) {
        STEP(0) STEP(1) STEP(2) STEP(3)
        STEP(4) STEP(5) STEP(6) STEP(7)
        // Flush this iteration's 8 staged steps: coalesced LDS read + NT store
        const f32x4_t v = *reinterpret_cast<const f32x4_t*>(
            &stage[((t0 & 8) + fstep) * 128 + felem]);
        __builtin_nontemporal_store(v,
            reinterpret_cast<f32x4_t*>(&out[(t0 + fstep) * RSZ + felem]));
    }
    #undef STEP
    #undef ACT
}

extern "C" void kernel_launch(void* const* d_in, const int* in_sizes, int n_in,
                              void* d_out, int out_size, void* d_ws, size_t ws_size,
                              hipStream_t stream) {
    const float* x     = (const float*)d_in[0];
    const float* w_in  = (const float*)d_in[1];
    const float* w_res = (const float*)d_in[2];
    float* out = (float*)d_out;

    proj_kernel<<<(BATCH * SEQ) / 32, 256, 0, stream>>>(x, w_in, out);
    scan_kernel<<<BATCH, 256, 0, stream>>>(w_res, out);
}

// Round 16
// 1231.095 us; speedup vs baseline: 1.0459x; 1.0459x over previous
//
#include <hip/hip_runtime.h>

#define BATCH 64
#define SEQ   4096
#define ISZ   64
#define RSZ   128

typedef float  f32x4_t __attribute__((ext_vector_type(4)));
typedef __fp16 f16x2_t __attribute__((ext_vector_type(2)));

__device__ __forceinline__ float fast_tanh(float x) {
    float e = __expf(2.0f * x);
    return 1.0f - 2.0f / (e + 1.0f);
}

__device__ __forceinline__ float dot2(f16x2_t a, f16x2_t b, float c) {
#if __has_builtin(__builtin_amdgcn_fdot2)
    return __builtin_amdgcn_fdot2(a, b, c, false);
#else
    return fmaf((float)a.x, (float)b.x, fmaf((float)a.y, (float)b.y, c));
#endif
}

// x + cross-lane(x) via DPP — pure VALU, no DS ops.
// 0xB1 = quad_perm[1,0,3,2] (xor1), 0x4E = quad_perm[2,3,0,1] (xor2),
// 0x141 = row_half_mirror (lane l <-> l^7 within each 8-lane half-row).
template <int CTRL>
__device__ __forceinline__ float dpp_add(float x) {
    int y = __builtin_amdgcn_update_dpp(0, __builtin_bit_cast(int, x),
                                        CTRL, 0xF, 0xF, true);
    return x + __builtin_bit_cast(float, y);
}

// ---------------------------------------------------------------------------
// Kernel 1: projection. out[row][r] = tanh(sum_j x[row][j] * w_in[r][j])
// (round-14 verbatim: scalar-FMA inner product was faster than pk_fma)
// ---------------------------------------------------------------------------
__global__ __launch_bounds__(256) void proj_kernel(
        const float* __restrict__ x, const float* __restrict__ w_in,
        float* __restrict__ out) {
    __shared__ float wT[ISZ][RSZ];
    __shared__ float xs[32][ISZ];

    const int tid = threadIdx.x;

    for (int idx = tid; idx < RSZ * ISZ / 4; idx += 256) {
        const int r  = idx >> 4;
        const int j4 = (idx & 15) << 2;
        const float4 v = reinterpret_cast<const float4*>(w_in)[idx];
        wT[j4 + 0][r] = v.x; wT[j4 + 1][r] = v.y;
        wT[j4 + 2][r] = v.z; wT[j4 + 3][r] = v.w;
    }
    const long row0 = (long)blockIdx.x * 32;
    #pragma unroll
    for (int q = 0; q < 2; ++q) {
        const int idx = tid + q * 256;
        reinterpret_cast<float4*>(&xs[0][0])[idx] =
            reinterpret_cast<const float4*>(x + row0 * ISZ)[idx];
    }
    __syncthreads();

    const int rq = tid & 31;
    const int rp = tid >> 5;
    const int r0 = rq << 2;
    const int ra = rp << 2;

    float acc[4][4] = {};
    #pragma unroll
    for (int j4 = 0; j4 < ISZ; j4 += 4) {
        float4 xv[4];
        #pragma unroll
        for (int m = 0; m < 4; ++m)
            xv[m] = *reinterpret_cast<const float4*>(&xs[ra + m][j4]);
        #pragma unroll
        for (int k = 0; k < 4; ++k) {
            const float4 w = *reinterpret_cast<const float4*>(&wT[j4 + k][r0]);
            #pragma unroll
            for (int m = 0; m < 4; ++m) {
                const float xm = k == 0 ? xv[m].x : k == 1 ? xv[m].y
                               : k == 2 ? xv[m].z : xv[m].w;
                acc[m][0] += xm * w.x; acc[m][1] += xm * w.y;
                acc[m][2] += xm * w.z; acc[m][3] += xm * w.w;
            }
        }
    }
    #pragma unroll
    for (int m = 0; m < 4; ++m) {
        float4 o;
        o.x = fast_tanh(acc[m][0]); o.y = fast_tanh(acc[m][1]);
        o.z = fast_tanh(acc[m][2]); o.w = fast_tanh(acc[m][3]);
        *reinterpret_cast<float4*>(&out[(row0 + ra + m) * RSZ + r0]) = o;
    }
}

// ---------------------------------------------------------------------------
// Kernel 2: sequential scan — ROUND-14 VERBATIM (1229 us proven best).
// One block per batch, 4 waves; lane (grp = lane>>3, sl = lane&7) does rows
// r0..r0+3 x k-slice [16sl,16sl+16); packed-f16-in-float h LDS (2
// ds_read_b128/lane, one float2 write); v_dot2_f32_f16 with 4 accumulators
// (8-deep — the r15 8-acc split regressed); 12-DPP reduce; 4 redundant ACTs;
// stage ring + NT flush; 4-deep u prefetch; raw s_barrier + lgkmcnt(0)-only
// wait. Float-typed LDS only (uint-typed LDS failed r11/r13).
// Step ~675 cyc = ds_read latency + dot + DPP + ACT + write/lgkm + barrier
// skew — the empirical floor across all structures measured (r6-r15).
// ---------------------------------------------------------------------------
__global__ __launch_bounds__(256) void scan_kernel(
        const float* __restrict__ w_res, float* __restrict__ io) {
    __shared__ float hq[2][80];          // packed f16x2-in-float, dbuf (64 used)
    __shared__ float stage[16 * 128];    // 8 KB ring, slot = t & 15

    const int tid  = threadIdx.x;
    const int lane = tid & 63;
    const int wave = tid >> 6;
    const int grp  = lane >> 3;          // 8 output groups of 4
    const int sl   = lane & 7;           // 8 k-slices of 16
    const int r0   = wave * 32 + grp * 4;
    const int kb   = sl * 16;

    // W_res rows r0..r0+3, cols kb..kb+15 -> f16x2 (32 VGPRs)
    f16x2_t w2[4][8];
    #pragma unroll
    for (int rr = 0; rr < 4; ++rr) {
        #pragma unroll
        for (int kk = 0; kk < 16; kk += 4) {
            const f32x4_t v = *reinterpret_cast<const f32x4_t*>(
                &w_res[(r0 + rr) * RSZ + kb + kk]);
            w2[rr][kk / 2]     = __builtin_amdgcn_cvt_pkrtz(v.x, v.y);
            w2[rr][kk / 2 + 1] = __builtin_amdgcn_cvt_pkrtz(v.z, v.w);
        }
    }

    for (int i = tid; i < 2 * 80; i += 256) (&hq[0][0])[i] = 0.0f;

    float* const out = io + (long)blockIdx.x * (SEQ * RSZ);
    const int hrd = 8 * sl;              // float index of k-slice base
    const int hwr = 16 * wave + 2 * grp; // float index of own packed pair

    // 4-deep u prefetch ring (float4 per lane at r0)
    float4 u[4];
    #pragma unroll
    for (int s = 0; s < 4; ++s)
        u[s] = *reinterpret_cast<const float4*>(&out[s * RSZ + r0]);
    float4 hreg = {0.f, 0.f, 0.f, 0.f};
    __syncthreads();

    // nh = 0.5*h + 0.5*tanh(v) = fma(0.5,h,0.5) - 1/(exp2(2*log2e*v)+1)
    #define ACT(HH, VV)                                                       \
        (fmaf(0.5f, (HH), 0.5f) -                                             \
         __builtin_amdgcn_rcpf(                                               \
             __builtin_amdgcn_exp2f((VV) * 2.885390082f) + 1.0f))

    #define STEP(S)                                                           \
    {                                                                         \
        int tp = t0 + (S) + 4;                                                \
        if (tp > SEQ - 1) tp = SEQ - 1;                                       \
        const float4 uc = u[(S) & 3];                                         \
        u[(S) & 3] = *reinterpret_cast<const float4*>(&out[tp * RSZ + r0]);   \
        const float4 p0 = *reinterpret_cast<const float4*>(                   \
            &hq[(S) & 1][hrd]);                                               \
        const float4 p1 = *reinterpret_cast<const float4*>(                   \
            &hq[(S) & 1][hrd + 4]);                                           \
        f16x2_t hv[8];                                                        \
        hv[0] = __builtin_bit_cast(f16x2_t, p0.x);                            \
        hv[1] = __builtin_bit_cast(f16x2_t, p0.y);                            \
        hv[2] = __builtin_bit_cast(f16x2_t, p0.z);                            \
        hv[3] = __builtin_bit_cast(f16x2_t, p0.w);                            \
        hv[4] = __builtin_bit_cast(f16x2_t, p1.x);                            \
        hv[5] = __builtin_bit_cast(f16x2_t, p1.y);                            \
        hv[6] = __builtin_bit_cast(f16x2_t, p1.z);                            \
        hv[7] = __builtin_bit_cast(f16x2_t, p1.w);                            \
        float a0 = 0.f, a1 = 0.f, a2 = 0.f, a3 = 0.f;                         \
        _Pragma("unroll")                                                     \
        for (int j = 0; j < 8; ++j) {                                         \
            a0 = dot2(hv[j], w2[0][j], a0);                                   \
            a1 = dot2(hv[j], w2[1][j], a1);                                   \
            a2 = dot2(hv[j], w2[2][j], a2);                                   \
            a3 = dot2(hv[j], w2[3][j], a3);                                   \
        }                                                                     \
        a0 = dpp_add<0xB1>(a0);  a1 = dpp_add<0xB1>(a1);                      \
        a2 = dpp_add<0xB1>(a2);  a3 = dpp_add<0xB1>(a3);                      \
        a0 = dpp_add<0x4E>(a0);  a1 = dpp_add<0x4E>(a1);                      \
        a2 = dpp_add<0x4E>(a2);  a3 = dpp_add<0x4E>(a3);                      \
        a0 = dpp_add<0x141>(a0); a1 = dpp_add<0x141>(a1);                     \
        a2 = dpp_add<0x141>(a2); a3 = dpp_add<0x141>(a3);                     \
        float4 nh;                                                            \
        nh.x = ACT(hreg.x, uc.x + a0);                                        \
        nh.y = ACT(hreg.y, uc.y + a1);                                        \
        nh.z = ACT(hreg.z, uc.z + a2);                                        \
        nh.w = ACT(hreg.w, uc.w + a3);                                        \
        hreg = nh;                                                            \
        if (sl == 0) {                                                        \
            float2 pv;                                                        \
            pv.x = __builtin_bit_cast(float,                                  \
                       __builtin_amdgcn_cvt_pkrtz(nh.x, nh.y));               \
            pv.y = __builtin_bit_cast(float,                                  \
                       __builtin_amdgcn_cvt_pkrtz(nh.z, nh.w));               \
            *reinterpret_cast<float2*>(&hq[1 - ((S) & 1)][hwr]) = pv;         \
        } else if (sl == 1) {                                                 \
            *reinterpret_cast<float4*>(                                       \
                &stage[((t0 & 8) + (S)) * 128 + r0]) = nh;                    \
        }                                                                     \
        asm volatile("s_waitcnt lgkmcnt(0)" ::: "memory");                    \
        __builtin_amdgcn_s_barrier();                                         \
        asm volatile("" ::: "memory");                                        \
    }

    const int fstep = tid >> 5;          // 0..7: which step of the half
    const int felem = (tid & 31) * 4;    // 0..124: element quad

    for (int t0 = 0; t0 < SEQ; t0 += 8) {
        STEP(0) STEP(1) STEP(2) STEP(3)
        STEP(4) STEP(5) STEP(6) STEP(7)
        // Flush this iteration's 8 staged steps: coalesced LDS read + NT store
        const f32x4_t v = *reinterpret_cast<const f32x4_t*>(
            &stage[((t0 & 8) + fstep) * 128 + felem]);
        __builtin_nontemporal_store(v,
            reinterpret_cast<f32x4_t*>(&out[(t0 + fstep) * RSZ + felem]));
    }
    #undef STEP
    #undef ACT
}

extern "C" void kernel_launch(void* const* d_in, const int* in_sizes, int n_in,
                              void* d_out, int out_size, void* d_ws, size_t ws_size,
                              hipStream_t stream) {
    const float* x     = (const float*)d_in[0];
    const float* w_in  = (const float*)d_in[1];
    const float* w_res = (const float*)d_in[2];
    float* out = (float*)d_out;

    proj_kernel<<<(BATCH * SEQ) / 32, 256, 0, stream>>>(x, w_in, out);
    scan_kernel<<<BATCH, 256, 0, stream>>>(w_res, out);
}